// Round 1
// baseline (1251.449 us; speedup 1.0000x reference)
//
#include <hip/hip_runtime.h>
#include <hip/hip_bf16.h>

#define GN 100000
#define GE 3200000
// IN_F = 256, OUT_F = 128

// ---------------- GEMM: h = x (N x 256) @ W (256 x 128), fp32 ----------------
// 128x128 block tile, BK=8, 256 threads, 8x8 micro-tile per thread.
__global__ __launch_bounds__(256) void gemm_kernel(const float* __restrict__ x,
                                                   const float* __restrict__ w,
                                                   float* __restrict__ h) {
    constexpr int BM = 128, BK = 8;
    __shared__ float As[BK][BM + 4];   // k-major (transposed at load)
    __shared__ float Bs[BK][128 + 4];
    const int tid = threadIdx.x;
    const int bm = blockIdx.x * BM;
    const int tr = tid / 16, tc = tid % 16;   // 16x16 thread grid

    float acc[8][8] = {};

    // A-load mapping: one float4 per thread: row = tid/2, half = tid%2
    const int arow = tid >> 1;          // 0..127
    const int ahalf = tid & 1;          // 0..1
    const int aRowG = bm + arow;
    const float* xrow = x + (size_t)(aRowG < GN ? aRowG : 0) * 256 + ahalf * 4;
    // B-load mapping: one float4 per thread: k = tid/32, col4 = tid%32
    const int bk = tid >> 5;            // 0..7
    const int bc = tid & 31;            // 0..31

    for (int k0 = 0; k0 < 256; k0 += BK) {
        float4 av = *(const float4*)(xrow + k0);
        float4 bv = *(const float4*)(w + (size_t)(k0 + bk) * 128 + bc * 4);
        __syncthreads();               // protect previous tile's readers
        As[ahalf * 4 + 0][arow] = av.x;
        As[ahalf * 4 + 1][arow] = av.y;
        As[ahalf * 4 + 2][arow] = av.z;
        As[ahalf * 4 + 3][arow] = av.w;
        *(float4*)&Bs[bk][bc * 4] = bv;
        __syncthreads();
#pragma unroll
        for (int k = 0; k < BK; ++k) {
            float4 a0 = *(const float4*)&As[k][tr * 8];
            float4 a1 = *(const float4*)&As[k][tr * 8 + 4];
            float4 b0 = *(const float4*)&Bs[k][tc * 8];
            float4 b1 = *(const float4*)&Bs[k][tc * 8 + 4];
            float ar[8] = {a0.x, a0.y, a0.z, a0.w, a1.x, a1.y, a1.z, a1.w};
            float br[8] = {b0.x, b0.y, b0.z, b0.w, b1.x, b1.y, b1.z, b1.w};
#pragma unroll
            for (int i = 0; i < 8; ++i)
#pragma unroll
                for (int j = 0; j < 8; ++j)
                    acc[i][j] += ar[i] * br[j];
        }
    }
#pragma unroll
    for (int i = 0; i < 8; ++i) {
        int row = bm + tr * 8 + i;
        if (row < GN) {
            float4 v0 = {acc[i][0], acc[i][1], acc[i][2], acc[i][3]};
            float4 v1 = {acc[i][4], acc[i][5], acc[i][6], acc[i][7]};
            *(float4*)&h[(size_t)row * 128 + tc * 8] = v0;
            *(float4*)&h[(size_t)row * 128 + tc * 8 + 4] = v1;
        }
    }
}

// ---------------- scores: s_l = h @ a[0:128], s_r = h @ a[128:256] ----------------
// one wave per row, 4 waves/block
__global__ __launch_bounds__(256) void score_kernel(const float* __restrict__ h,
                                                    const float* __restrict__ a,
                                                    float* __restrict__ s_l,
                                                    float* __restrict__ s_r) {
    int row = (blockIdx.x * 256 + threadIdx.x) >> 6;
    int lane = threadIdx.x & 63;
    if (row >= GN) return;
    float h0 = h[(size_t)row * 128 + lane];
    float h1 = h[(size_t)row * 128 + 64 + lane];
    float pl = h0 * a[lane] + h1 * a[64 + lane];
    float pr = h0 * a[128 + lane] + h1 * a[192 + lane];
#pragma unroll
    for (int off = 32; off; off >>= 1) {
        pl += __shfl_xor(pl, off, 64);
        pr += __shfl_xor(pr, off, 64);
    }
    if (lane == 0) { s_l[row] = pl; s_r[row] = pr; }
}

// ---------------- CSR build ----------------
__global__ __launch_bounds__(256) void hist_kernel(const int* __restrict__ src, int* __restrict__ deg) {
    int i = blockIdx.x * 256 + threadIdx.x;
    if (i < GE) atomicAdd(&deg[src[i]], 1);
}

__global__ __launch_bounds__(1024) void scan_kernel(const int* __restrict__ deg,
                                                    int* __restrict__ rowptr,
                                                    int* __restrict__ cursor) {
    __shared__ int sums[1024];
    const int t = threadIdx.x;
    const int ITEMS = (GN + 1023) / 1024;   // 98
    const int base = t * ITEMS;
    int s = 0;
    for (int i = 0; i < ITEMS; ++i) {
        int idx = base + i;
        if (idx < GN) s += deg[idx];
    }
    sums[t] = s;
    __syncthreads();
    for (int off = 1; off < 1024; off <<= 1) {
        int v = (t >= off) ? sums[t - off] : 0;
        __syncthreads();
        sums[t] += v;
        __syncthreads();
    }
    int run = sums[t] - s;   // exclusive prefix
    for (int i = 0; i < ITEMS; ++i) {
        int idx = base + i;
        if (idx < GN) {
            rowptr[idx] = run;
            cursor[idx] = run;
            run += deg[idx];
        }
    }
    if (t == 1023) rowptr[GN] = sums[1023];
}

__global__ __launch_bounds__(256) void scatter_kernel(const int* __restrict__ ei,
                                                      int* __restrict__ cursor,
                                                      int* __restrict__ adj) {
    int i = blockIdx.x * 256 + threadIdx.x;
    if (i < GE) {
        int s = ei[i];
        int d = ei[GE + i];
        int pos = atomicAdd(&cursor[s], 1);
        adj[pos] = d;
    }
}

// ---------------- per-node softmax + weighted aggregation ----------------
// one wave per node; phase 1: lane-parallel online softmax over edges;
// phase 2: feature-parallel (float2/lane) accumulation of alpha * h[dst].
__global__ __launch_bounds__(256) void aggregate_kernel(const float* __restrict__ h,
                                                        const float* __restrict__ s_l,
                                                        const float* __restrict__ s_r,
                                                        const int* __restrict__ rowptr,
                                                        const int* __restrict__ adj,
                                                        float* __restrict__ out) {
    int node = blockIdx.x * 4 + (threadIdx.x >> 6);
    int lane = threadIdx.x & 63;
    if (node >= GN) return;
    int beg = rowptr[node], end = rowptr[node + 1];
    float sl = s_l[node];

    // online softmax, lane-parallel over edges  (init -1e30, not -inf: keeps exp args finite)
    float m = -1e30f, d = 0.f;
    for (int i = beg + lane; i < end; i += 64) {
        int dst = adj[i];
        float e = sl + s_r[dst];
        e = (e >= 0.f) ? e : 0.2f * e;
        float mn = fmaxf(m, e);
        d = d * __expf(m - mn) + __expf(e - mn);
        m = mn;
    }
#pragma unroll
    for (int off = 32; off; off >>= 1) {
        float m2 = __shfl_xor(m, off, 64);
        float d2 = __shfl_xor(d, off, 64);
        float mn = fmaxf(m, m2);
        d = d * __expf(m - mn) + d2 * __expf(m2 - mn);
        m = mn;
    }
    float inv = 1.f / (d + 1e-16f);

    float2 acc = {0.f, 0.f};
    const float2* h2 = (const float2*)h;
    for (int i = beg; i < end; ++i) {
        int dst = adj[i];                       // wave-uniform broadcast
        float e = sl + s_r[dst];
        e = (e >= 0.f) ? e : 0.2f * e;
        float alpha = __expf(e - m) * inv;
        float2 hv = h2[(size_t)dst * 64 + lane];
        acc.x += alpha * hv.x;
        acc.y += alpha * hv.y;
    }
    ((float2*)out)[(size_t)node * 64 + lane] = acc;   // also zeros empty segments
}

extern "C" void kernel_launch(void* const* d_in, const int* in_sizes, int n_in,
                              void* d_out, int out_size, void* d_ws, size_t ws_size,
                              hipStream_t stream) {
    const float* x  = (const float*)d_in[0];
    const int*   ei = (const int*)d_in[1];      // [0,E) = src, [E,2E) = dst
    const float* w  = (const float*)d_in[2];
    const float* a  = (const float*)d_in[3];
    float* out = (float*)d_out;

    // workspace layout (4-byte words)
    float* h      = (float*)d_ws;                       // N*128
    float* s_l    = h + (size_t)GN * 128;               // N
    float* s_r    = s_l + GN;                           // N
    int*   deg    = (int*)(s_r + GN);                   // N
    int*   rowptr = deg + GN;                           // N+1
    int*   cursor = rowptr + GN + 1;                    // N
    int*   adj    = cursor + GN;                        // E

    hipMemsetAsync(deg, 0, GN * sizeof(int), stream);

    gemm_kernel<<<(GN + 127) / 128, 256, 0, stream>>>(x, w, h);
    score_kernel<<<(GN * 64 + 255) / 256, 256, 0, stream>>>(h, a, s_l, s_r);
    hist_kernel<<<(GE + 255) / 256, 256, 0, stream>>>(ei, deg);
    scan_kernel<<<1, 1024, 0, stream>>>(deg, rowptr, cursor);
    scatter_kernel<<<(GE + 255) / 256, 256, 0, stream>>>(ei, cursor, adj);
    aggregate_kernel<<<(GN + 3) / 4, 256, 0, stream>>>(h, s_l, s_r, rowptr, adj, out);
}

// Round 2
// 966.133 us; speedup vs baseline: 1.2953x; 1.2953x over previous
//
#include <hip/hip_runtime.h>

#define GN 100000
#define GE 3200000
#define CAP 128

typedef __attribute__((ext_vector_type(8))) short bf16x8;
typedef __attribute__((ext_vector_type(4))) float f32x4;

__device__ __forceinline__ unsigned short f2bf(float f) {
    unsigned u = __float_as_uint(f);
    u += 0x7fffu + ((u >> 16) & 1u);          // RNE
    return (unsigned short)(u >> 16);
}
__device__ __forceinline__ float bf2f(unsigned short u) {
    return __uint_as_float(((unsigned)u) << 16);
}

// ---------------- W prep: w fp32 [256][128] -> wT bf16 [128][256] ----------------
__global__ __launch_bounds__(256) void wprep_kernel(const float* __restrict__ w,
                                                    unsigned short* __restrict__ wT) {
    int flat4 = blockIdx.x * 256 + threadIdx.x;     // 0..8191
    if (flat4 >= 256 * 128 / 4) return;
    int k  = flat4 >> 5;
    int n4 = (flat4 & 31) * 4;
    float4 v = ((const float4*)w)[flat4];
    wT[(size_t)(n4 + 0) * 256 + k] = f2bf(v.x);
    wT[(size_t)(n4 + 1) * 256 + k] = f2bf(v.y);
    wT[(size_t)(n4 + 2) * 256 + k] = f2bf(v.z);
    wT[(size_t)(n4 + 3) * 256 + k] = f2bf(v.w);
}

// ---------------- GEMM: h = x @ W via bf16 MFMA; scores fused in epilogue ----------------
// block 256 = 4 waves (2x2), each wave 64x64 via 4x4 mfma_f32_16x16x32_bf16 tiles.
// A staged fp32->bf16 in LDS (pad 40 for uniform bank use); B frags from L2-resident wT.
__global__ __launch_bounds__(256) void gemm_kernel(const float* __restrict__ x,
                                                   const unsigned short* __restrict__ wT,
                                                   const float* __restrict__ a,
                                                   unsigned short* __restrict__ hq,
                                                   float* __restrict__ s_l,
                                                   float* __restrict__ s_r) {
    __shared__ unsigned short As[128][40];
    const int tid  = threadIdx.x;
    const int lane = tid & 63, wid = tid >> 6;
    const int l16  = lane & 15, quad = lane >> 4;
    const int wm   = (wid >> 1) * 64, wn = (wid & 1) * 64;
    const int bm   = blockIdx.x * 128;

    f32x4 acc[4][4] = {};

    const int arow = tid >> 1, ahalf = tid & 1;
    int gr = bm + arow; if (gr >= GN) gr = GN - 1;   // clamp loads; stores guarded
    const float* xrow = x + (size_t)gr * 256 + ahalf * 16;

    for (int k0 = 0; k0 < 256; k0 += 32) {
        float4 f0 = *(const float4*)(xrow + k0);
        float4 f1 = *(const float4*)(xrow + k0 + 4);
        float4 f2 = *(const float4*)(xrow + k0 + 8);
        float4 f3 = *(const float4*)(xrow + k0 + 12);
        bf16x8 s0, s1;
        s0[0] = f2bf(f0.x); s0[1] = f2bf(f0.y); s0[2] = f2bf(f0.z); s0[3] = f2bf(f0.w);
        s0[4] = f2bf(f1.x); s0[5] = f2bf(f1.y); s0[6] = f2bf(f1.z); s0[7] = f2bf(f1.w);
        s1[0] = f2bf(f2.x); s1[1] = f2bf(f2.y); s1[2] = f2bf(f2.z); s1[3] = f2bf(f2.w);
        s1[4] = f2bf(f3.x); s1[5] = f2bf(f3.y); s1[6] = f2bf(f3.z); s1[7] = f2bf(f3.w);
        __syncthreads();                     // protect previous tile's readers
        *(bf16x8*)&As[arow][ahalf * 16]     = s0;
        *(bf16x8*)&As[arow][ahalf * 16 + 8] = s1;
        __syncthreads();
        bf16x8 af[4], bfr[4];
#pragma unroll
        for (int t = 0; t < 4; ++t) {
            af[t]  = *(const bf16x8*)&As[wm + t * 16 + l16][quad * 8];
            bfr[t] = *(const bf16x8*)(wT + (size_t)(wn + t * 16 + l16) * 256 + k0 + quad * 8);
        }
#pragma unroll
        for (int ti = 0; ti < 4; ++ti)
#pragma unroll
            for (int tj = 0; tj < 4; ++tj)
                acc[ti][tj] = __builtin_amdgcn_mfma_f32_16x16x32_bf16(af[ti], bfr[tj], acc[ti][tj], 0, 0, 0);
    }

    // epilogue: h store (bf16) + fused fp32 scores
    float alv[4], arv[4];
#pragma unroll
    for (int tj = 0; tj < 4; ++tj) {
        alv[tj] = a[wn + tj * 16 + l16];
        arv[tj] = a[128 + wn + tj * 16 + l16];
    }
#pragma unroll
    for (int ti = 0; ti < 4; ++ti) {
        float slp[4], srp[4];
#pragma unroll
        for (int r = 0; r < 4; ++r) {
            int row = bm + wm + ti * 16 + quad * 4 + r;
            float v0 = acc[ti][0][r], v1 = acc[ti][1][r], v2 = acc[ti][2][r], v3 = acc[ti][3][r];
            if (row < GN) {
                unsigned short* hp = hq + (size_t)row * 128 + wn + l16;
                hp[0]  = f2bf(v0);
                hp[16] = f2bf(v1);
                hp[32] = f2bf(v2);
                hp[48] = f2bf(v3);
            }
            slp[r] = v0 * alv[0] + v1 * alv[1] + v2 * alv[2] + v3 * alv[3];
            srp[r] = v0 * arv[0] + v1 * arv[1] + v2 * arv[2] + v3 * arv[3];
        }
#pragma unroll
        for (int off = 1; off < 16; off <<= 1)
#pragma unroll
            for (int r = 0; r < 4; ++r) {
                slp[r] += __shfl_xor(slp[r], off, 64);
                srp[r] += __shfl_xor(srp[r], off, 64);
            }
        if (l16 == 0) {
#pragma unroll
            for (int r = 0; r < 4; ++r) {
                int row = bm + wm + ti * 16 + quad * 4 + r;
                if (row < GN) {
                    atomicAdd(&s_l[row], slp[r]);
                    atomicAdd(&s_r[row], srp[r]);
                }
            }
        }
    }
}

// ---------------- CSR build ----------------
__global__ __launch_bounds__(256) void hist_kernel(const int* __restrict__ src, int* __restrict__ deg) {
    int i = blockIdx.x * 256 + threadIdx.x;
    if (i < GE) atomicAdd(&deg[src[i]], 1);
}

__global__ __launch_bounds__(1024) void scan_kernel(const int* __restrict__ deg,
                                                    int* __restrict__ rowptr,
                                                    int* __restrict__ cursor) {
    __shared__ int sums[1024];
    const int t = threadIdx.x;
    const int ITEMS = (GN + 1023) / 1024;   // 98
    const int base = t * ITEMS;
    int s = 0;
    for (int i = 0; i < ITEMS; ++i) {
        int idx = base + i;
        if (idx < GN) s += deg[idx];
    }
    sums[t] = s;
    __syncthreads();
    for (int off = 1; off < 1024; off <<= 1) {
        int v = (t >= off) ? sums[t - off] : 0;
        __syncthreads();
        sums[t] += v;
        __syncthreads();
    }
    int run = sums[t] - s;   // exclusive prefix
    for (int i = 0; i < ITEMS; ++i) {
        int idx = base + i;
        if (idx < GN) {
            rowptr[idx] = run;
            cursor[idx] = run;
            run += deg[idx];
        }
    }
    if (t == 1023) rowptr[GN] = sums[1023];
}

__global__ __launch_bounds__(256) void scatter_kernel(const int* __restrict__ ei,
                                                      int* __restrict__ cursor,
                                                      int* __restrict__ adj) {
    int i = blockIdx.x * 256 + threadIdx.x;
    if (i < GE) {
        int s = ei[i];
        int d = ei[GE + i];
        int pos = atomicAdd(&cursor[s], 1);
        adj[pos] = d;
    }
}

// ---------------- per-node softmax + weighted aggregation (bf16 h) ----------------
// one wave/node. Phase 1: lane-parallel online softmax; cache dst+e in LDS.
// Phase 1.5: e -> normalized alpha in LDS. Phase 2: serial edge loop, 4-way
// unrolled independent 256B h-row gathers (only dependent load in the chain).
__global__ __launch_bounds__(256) void aggregate_kernel(const ushort2* __restrict__ h2,
                                                        const float* __restrict__ s_l,
                                                        const float* __restrict__ s_r,
                                                        const int* __restrict__ rowptr,
                                                        const int* __restrict__ adj,
                                                        float* __restrict__ out) {
    __shared__ int   s_dst[4][CAP];
    __shared__ float s_al[4][CAP];
    const int wid = threadIdx.x >> 6, lane = threadIdx.x & 63;
    const int node = blockIdx.x * 4 + wid;            // grid = GN/4 exactly
    const int beg = rowptr[node], end = rowptr[node + 1];
    const int deg = end - beg;
    const float sl = s_l[node];

    float m = -1e30f, d = 0.f;
    for (int j = lane; j < deg; j += 64) {
        int dst = adj[beg + j];
        float e = sl + s_r[dst];
        e = (e >= 0.f) ? e : 0.2f * e;
        if (j < CAP) { s_dst[wid][j] = dst; s_al[wid][j] = e; }
        float mn = fmaxf(m, e);
        d = d * __expf(m - mn) + __expf(e - mn);
        m = mn;
    }
#pragma unroll
    for (int off = 32; off; off >>= 1) {
        float m2 = __shfl_xor(m, off, 64);
        float d2 = __shfl_xor(d, off, 64);
        float mn = fmaxf(m, m2);
        d = d * __expf(m - mn) + d2 * __expf(m2 - mn);
        m = mn;
    }
    float inv = 1.f / (d + 1e-16f);
    __syncthreads();
    const int n2 = deg < CAP ? deg : CAP;
    for (int j = lane; j < n2; j += 64)
        s_al[wid][j] = __expf(s_al[wid][j] - m) * inv;
    __syncthreads();

    float2 acc = {0.f, 0.f};
    int j = 0;
    for (; j + 4 <= n2; j += 4) {
        int   d0 = s_dst[wid][j],     d1 = s_dst[wid][j + 1];
        int   d2i = s_dst[wid][j + 2], d3 = s_dst[wid][j + 3];
        float a0 = s_al[wid][j],      a1 = s_al[wid][j + 1];
        float a2 = s_al[wid][j + 2],  a3 = s_al[wid][j + 3];
        ushort2 v0 = h2[(size_t)d0 * 64 + lane];
        ushort2 v1 = h2[(size_t)d1 * 64 + lane];
        ushort2 v2 = h2[(size_t)d2i * 64 + lane];
        ushort2 v3 = h2[(size_t)d3 * 64 + lane];
        acc.x += a0 * bf2f(v0.x) + a1 * bf2f(v1.x) + a2 * bf2f(v2.x) + a3 * bf2f(v3.x);
        acc.y += a0 * bf2f(v0.y) + a1 * bf2f(v1.y) + a2 * bf2f(v2.y) + a3 * bf2f(v3.y);
    }
    for (; j < n2; ++j) {
        int d0 = s_dst[wid][j]; float a0 = s_al[wid][j];
        ushort2 v0 = h2[(size_t)d0 * 64 + lane];
        acc.x += a0 * bf2f(v0.x); acc.y += a0 * bf2f(v0.y);
    }
    for (; j < deg; ++j) {                            // slow path: deg > CAP
        int dst = adj[beg + j];
        float e = sl + s_r[dst];
        e = (e >= 0.f) ? e : 0.2f * e;
        float a0 = __expf(e - m) * inv;
        ushort2 v0 = h2[(size_t)dst * 64 + lane];
        acc.x += a0 * bf2f(v0.x); acc.y += a0 * bf2f(v0.y);
    }
    ((float2*)out)[(size_t)node * 64 + lane] = acc;
}

extern "C" void kernel_launch(void* const* d_in, const int* in_sizes, int n_in,
                              void* d_out, int out_size, void* d_ws, size_t ws_size,
                              hipStream_t stream) {
    const float* x  = (const float*)d_in[0];
    const int*   ei = (const int*)d_in[1];      // [0,E) = src, [E,2E) = dst
    const float* w  = (const float*)d_in[2];
    const float* a  = (const float*)d_in[3];
    float* out = (float*)d_out;

    // workspace layout
    unsigned short* hq = (unsigned short*)d_ws;             // GN*128 bf16
    float* s_l   = (float*)(hq + (size_t)GN * 128);         // GN
    float* s_r   = s_l + GN;                                // GN
    int*   deg   = (int*)(s_r + GN);                        // GN
    int*   rowptr= deg + GN;                                // GN+1
    int*   cursor= rowptr + GN + 1;                         // GN
    int*   adj   = cursor + GN;                             // GE
    unsigned short* wT = (unsigned short*)(adj + GE);       // 128*256 bf16

    hipMemsetAsync(s_l, 0, (size_t)3 * GN * sizeof(float), stream);  // s_l, s_r, deg

    wprep_kernel<<<32, 256, 0, stream>>>(w, wT);
    gemm_kernel<<<(GN + 127) / 128, 256, 0, stream>>>(x, wT, a, hq, s_l, s_r);
    hist_kernel<<<(GE + 255) / 256, 256, 0, stream>>>(ei, deg);
    scan_kernel<<<1, 1024, 0, stream>>>(deg, rowptr, cursor);
    scatter_kernel<<<(GE + 255) / 256, 256, 0, stream>>>(ei, cursor, adj);
    aggregate_kernel<<<GN / 4, 256, 0, stream>>>((const ushort2*)hq, s_l, s_r, rowptr, adj, out);
}

// Round 3
// 412.708 us; speedup vs baseline: 3.0323x; 2.3410x over previous
//
#include <hip/hip_runtime.h>

#define GN 100000
#define GE 3200000
#define CAP 128
#define NB 391          // coarse buckets: src >> 8, 256 nodes each
#define CHUNK 4096      // edges per bin-pass block

typedef __attribute__((ext_vector_type(8))) short bf16x8;
typedef __attribute__((ext_vector_type(4))) float f32x4;

__device__ __forceinline__ unsigned short f2bf(float f) {
    unsigned u = __float_as_uint(f);
    u += 0x7fffu + ((u >> 16) & 1u);          // RNE
    return (unsigned short)(u >> 16);
}
__device__ __forceinline__ float bf2f(unsigned short u) {
    return __uint_as_float(((unsigned)u) << 16);
}

// ---------------- W prep: w fp32 [256][128] -> wT bf16 [128][256] ----------------
__global__ __launch_bounds__(256) void wprep_kernel(const float* __restrict__ w,
                                                    unsigned short* __restrict__ wT) {
    int flat4 = blockIdx.x * 256 + threadIdx.x;     // 0..8191
    if (flat4 >= 256 * 128 / 4) return;
    int k  = flat4 >> 5;
    int n4 = (flat4 & 31) * 4;
    float4 v = ((const float4*)w)[flat4];
    wT[(size_t)(n4 + 0) * 256 + k] = f2bf(v.x);
    wT[(size_t)(n4 + 1) * 256 + k] = f2bf(v.y);
    wT[(size_t)(n4 + 2) * 256 + k] = f2bf(v.z);
    wT[(size_t)(n4 + 3) * 256 + k] = f2bf(v.w);
}

// ---------------- GEMM: h = x @ W via bf16 MFMA; scores fused in epilogue ----------------
__global__ __launch_bounds__(256) void gemm_kernel(const float* __restrict__ x,
                                                   const unsigned short* __restrict__ wT,
                                                   const float* __restrict__ a,
                                                   unsigned short* __restrict__ hq,
                                                   float* __restrict__ s_l,
                                                   float* __restrict__ s_r) {
    __shared__ unsigned short As[128][40];
    const int tid  = threadIdx.x;
    const int lane = tid & 63, wid = tid >> 6;
    const int l16  = lane & 15, quad = lane >> 4;
    const int wm   = (wid >> 1) * 64, wn = (wid & 1) * 64;
    const int bm   = blockIdx.x * 128;

    f32x4 acc[4][4] = {};

    const int arow = tid >> 1, ahalf = tid & 1;
    int gr = bm + arow; if (gr >= GN) gr = GN - 1;   // clamp loads; stores guarded
    const float* xrow = x + (size_t)gr * 256 + ahalf * 16;

    for (int k0 = 0; k0 < 256; k0 += 32) {
        float4 f0 = *(const float4*)(xrow + k0);
        float4 f1 = *(const float4*)(xrow + k0 + 4);
        float4 f2 = *(const float4*)(xrow + k0 + 8);
        float4 f3 = *(const float4*)(xrow + k0 + 12);
        bf16x8 s0, s1;
        s0[0] = f2bf(f0.x); s0[1] = f2bf(f0.y); s0[2] = f2bf(f0.z); s0[3] = f2bf(f0.w);
        s0[4] = f2bf(f1.x); s0[5] = f2bf(f1.y); s0[6] = f2bf(f1.z); s0[7] = f2bf(f1.w);
        s1[0] = f2bf(f2.x); s1[1] = f2bf(f2.y); s1[2] = f2bf(f2.z); s1[3] = f2bf(f2.w);
        s1[4] = f2bf(f3.x); s1[5] = f2bf(f3.y); s1[6] = f2bf(f3.z); s1[7] = f2bf(f3.w);
        __syncthreads();                     // protect previous tile's readers
        *(bf16x8*)&As[arow][ahalf * 16]     = s0;
        *(bf16x8*)&As[arow][ahalf * 16 + 8] = s1;
        __syncthreads();
        bf16x8 af[4], bfr[4];
#pragma unroll
        for (int t = 0; t < 4; ++t) {
            af[t]  = *(const bf16x8*)&As[wm + t * 16 + l16][quad * 8];
            bfr[t] = *(const bf16x8*)(wT + (size_t)(wn + t * 16 + l16) * 256 + k0 + quad * 8);
        }
#pragma unroll
        for (int ti = 0; ti < 4; ++ti)
#pragma unroll
            for (int tj = 0; tj < 4; ++tj)
                acc[ti][tj] = __builtin_amdgcn_mfma_f32_16x16x32_bf16(af[ti], bfr[tj], acc[ti][tj], 0, 0, 0);
    }

    float alv[4], arv[4];
#pragma unroll
    for (int tj = 0; tj < 4; ++tj) {
        alv[tj] = a[wn + tj * 16 + l16];
        arv[tj] = a[128 + wn + tj * 16 + l16];
    }
#pragma unroll
    for (int ti = 0; ti < 4; ++ti) {
        float slp[4], srp[4];
#pragma unroll
        for (int r = 0; r < 4; ++r) {
            int row = bm + wm + ti * 16 + quad * 4 + r;
            float v0 = acc[ti][0][r], v1 = acc[ti][1][r], v2 = acc[ti][2][r], v3 = acc[ti][3][r];
            if (row < GN) {
                unsigned short* hp = hq + (size_t)row * 128 + wn + l16;
                hp[0]  = f2bf(v0);
                hp[16] = f2bf(v1);
                hp[32] = f2bf(v2);
                hp[48] = f2bf(v3);
            }
            slp[r] = v0 * alv[0] + v1 * alv[1] + v2 * alv[2] + v3 * alv[3];
            srp[r] = v0 * arv[0] + v1 * arv[1] + v2 * arv[2] + v3 * arv[3];
        }
#pragma unroll
        for (int off = 1; off < 16; off <<= 1)
#pragma unroll
            for (int r = 0; r < 4; ++r) {
                slp[r] += __shfl_xor(slp[r], off, 64);
                srp[r] += __shfl_xor(srp[r], off, 64);
            }
        if (l16 == 0) {
#pragma unroll
            for (int r = 0; r < 4; ++r) {
                int row = bm + wm + ti * 16 + quad * 4 + r;
                if (row < GN) {
                    atomicAdd(&s_l[row], slp[r]);
                    atomicAdd(&s_r[row], srp[r]);
                }
            }
        }
    }
}

// ---------------- CSR build, pass 1: coarse bucket histogram ----------------
__global__ __launch_bounds__(256) void bhist_kernel(const int* __restrict__ src,
                                                    int* __restrict__ bcnt) {
    __shared__ int bh[NB];
    const int tid = threadIdx.x;
    for (int j = tid; j < NB; j += 256) bh[j] = 0;
    __syncthreads();
    const int base = blockIdx.x * CHUNK;
    const int cnt = min(CHUNK, GE - base);
    for (int i = tid; i < cnt; i += 256) atomicAdd(&bh[src[base + i] >> 8], 1);
    __syncthreads();
    for (int j = tid; j < NB; j += 256)
        if (bh[j]) atomicAdd(&bcnt[j], bh[j]);
}

// ---------------- CSR build, pass 2: bucket exclusive scan (one wave) ----------------
__global__ __launch_bounds__(64) void bscan_kernel(const int* __restrict__ bcnt,
                                                   int* __restrict__ bbase,
                                                   int* __restrict__ bcursor) {
    __shared__ int arr[NB];
    const int tid = threadIdx.x;
    for (int j = tid; j < NB; j += 64) arr[j] = bcnt[j];
    __syncthreads();
    int carry = 0;
    for (int b0 = 0; b0 < NB; b0 += 64) {
        int idx = b0 + tid;
        int v = (idx < NB) ? arr[idx] : 0;
        int x = v;
#pragma unroll
        for (int off = 1; off < 64; off <<= 1) {
            int y = __shfl_up(x, off, 64);
            if (tid >= off) x += y;
        }
        if (idx < NB) { bbase[idx] = carry + x - v; bcursor[idx] = carry + x - v; }
        carry += __shfl(x, 63, 64);
    }
    if (tid == 0) bbase[NB] = carry;
}

// ---------------- CSR build, pass 3: per-chunk counting sort -> coalesced runs ----------------
// entry = (srcLow8 << 17) | dst17   (dst < 131072, srcLow = src & 255)
__global__ __launch_bounds__(256) void bin_kernel(const int* __restrict__ ei,
                                                  int* __restrict__ bcursor,
                                                  unsigned* __restrict__ binned) {
    __shared__ int h_cnt[NB];
    __shared__ int h_base[NB + 1];
    __shared__ int h_gpos[NB];
    __shared__ int h_cur[NB];
    __shared__ unsigned sbuf[CHUNK];
    const int tid = threadIdx.x;
    const int base = blockIdx.x * CHUNK;
    const int cnt = min(CHUNK, GE - base);

    int srcv[CHUNK / 256], dstv[CHUNK / 256];
#pragma unroll
    for (int i = 0; i < CHUNK / 256; ++i) {
        int idx = tid + i * 256;
        if (idx < cnt) { srcv[i] = ei[base + idx]; dstv[i] = ei[GE + base + idx]; }
        else srcv[i] = -1;
    }
    for (int j = tid; j < NB; j += 256) h_cnt[j] = 0;
    __syncthreads();
#pragma unroll
    for (int i = 0; i < CHUNK / 256; ++i)
        if (srcv[i] >= 0) atomicAdd(&h_cnt[srcv[i] >> 8], 1);
    __syncthreads();
    if (tid < 64) {                      // wave0 exclusive scan of h_cnt -> h_base
        int carry = 0;
        for (int b0 = 0; b0 < NB; b0 += 64) {
            int idx = b0 + tid;
            int v = (idx < NB) ? h_cnt[idx] : 0;
            int x = v;
#pragma unroll
            for (int off = 1; off < 64; off <<= 1) {
                int y = __shfl_up(x, off, 64);
                if (tid >= off) x += y;
            }
            if (idx < NB) h_base[idx] = carry + x - v;
            carry += __shfl(x, 63, 64);
        }
        if (tid == 0) h_base[NB] = carry;
    }
    __syncthreads();
    for (int j = tid; j < NB; j += 256) {
        h_cur[j] = h_base[j];
        int c = h_cnt[j];
        if (c) h_gpos[j] = atomicAdd(&bcursor[j], c);   // reserve run in bucket region
    }
    __syncthreads();
#pragma unroll
    for (int i = 0; i < CHUNK / 256; ++i)
        if (srcv[i] >= 0) {
            int b = srcv[i] >> 8;
            int p = atomicAdd(&h_cur[b], 1);
            sbuf[p] = ((unsigned)(srcv[i] & 255) << 17) | (unsigned)dstv[i];
        }
    __syncthreads();
    for (int p = tid; p < cnt; p += 256) {   // coalesced run copy-out
        int lo = 0, hi = NB - 1;             // largest b with h_base[b] <= p
        while (lo < hi) {
            int mid = (lo + hi + 1) >> 1;
            if (h_base[mid] <= p) lo = mid; else hi = mid - 1;
        }
        binned[h_gpos[lo] + (p - h_base[lo])] = sbuf[p];
    }
}

// ---------------- CSR build, pass 4: per-bucket fine scatter (exclusive 32KB window) ----------------
// also produces rowptr (replaces global node hist + scan)
__global__ __launch_bounds__(256) void fine_kernel(const unsigned* __restrict__ binned,
                                                   const int* __restrict__ bbase,
                                                   int* __restrict__ rowptr,
                                                   int* __restrict__ adj) {
    __shared__ int n_cnt[256];
    __shared__ int n_base[257];
    __shared__ int n_cur[256];
    const int b = blockIdx.x;
    const int tid = threadIdx.x;
    const int node0 = b * 256;
    const int nn = min(256, GN - node0);
    const int beg = bbase[b], end = bbase[b + 1];
    n_cnt[tid] = 0;
    __syncthreads();
    for (int p = beg + tid; p < end; p += 256)
        atomicAdd(&n_cnt[binned[p] >> 17], 1);
    __syncthreads();
    if (tid < 64) {
        int carry = 0;
        for (int b0 = 0; b0 < 256; b0 += 64) {
            int idx = b0 + tid;
            int v = n_cnt[idx];
            int x = v;
#pragma unroll
            for (int off = 1; off < 64; off <<= 1) {
                int y = __shfl_up(x, off, 64);
                if (tid >= off) x += y;
            }
            n_base[idx] = carry + x - v;
            carry += __shfl(x, 63, 64);
        }
        if (tid == 0) n_base[256] = carry;
    }
    __syncthreads();
    if (tid < nn) rowptr[node0 + tid] = beg + n_base[tid];
    if (b == NB - 1 && tid == 0) rowptr[GN] = end;
    n_cur[tid] = n_base[tid];
    __syncthreads();
    for (int p = beg + tid; p < end; p += 256) {
        unsigned e = binned[p];
        int s = e >> 17, d = (int)(e & 0x1FFFFu);
        int pos = atomicAdd(&n_cur[s], 1);
        adj[beg + pos] = d;
    }
}

// ---------------- per-node softmax + weighted aggregation (bf16 h) ----------------
__global__ __launch_bounds__(256) void aggregate_kernel(const ushort2* __restrict__ h2,
                                                        const float* __restrict__ s_l,
                                                        const float* __restrict__ s_r,
                                                        const int* __restrict__ rowptr,
                                                        const int* __restrict__ adj,
                                                        float* __restrict__ out) {
    __shared__ int   s_dst[4][CAP];
    __shared__ float s_al[4][CAP];
    const int wid = threadIdx.x >> 6, lane = threadIdx.x & 63;
    const int node = blockIdx.x * 4 + wid;            // grid = GN/4 exactly
    const int beg = rowptr[node], end = rowptr[node + 1];
    const int deg = end - beg;
    const float sl = s_l[node];

    float m = -1e30f, d = 0.f;
    for (int j = lane; j < deg; j += 64) {
        int dst = adj[beg + j];
        float e = sl + s_r[dst];
        e = (e >= 0.f) ? e : 0.2f * e;
        if (j < CAP) { s_dst[wid][j] = dst; s_al[wid][j] = e; }
        float mn = fmaxf(m, e);
        d = d * __expf(m - mn) + __expf(e - mn);
        m = mn;
    }
#pragma unroll
    for (int off = 32; off; off >>= 1) {
        float m2 = __shfl_xor(m, off, 64);
        float d2 = __shfl_xor(d, off, 64);
        float mn = fmaxf(m, m2);
        d = d * __expf(m - mn) + d2 * __expf(m2 - mn);
        m = mn;
    }
    float inv = 1.f / (d + 1e-16f);
    __syncthreads();
    const int n2 = deg < CAP ? deg : CAP;
    for (int j = lane; j < n2; j += 64)
        s_al[wid][j] = __expf(s_al[wid][j] - m) * inv;
    __syncthreads();

    float2 acc = {0.f, 0.f};
    int j = 0;
    for (; j + 4 <= n2; j += 4) {
        int   d0 = s_dst[wid][j],      d1 = s_dst[wid][j + 1];
        int   d2i = s_dst[wid][j + 2], d3 = s_dst[wid][j + 3];
        float a0 = s_al[wid][j],       a1 = s_al[wid][j + 1];
        float a2 = s_al[wid][j + 2],   a3 = s_al[wid][j + 3];
        ushort2 v0 = h2[(size_t)d0 * 64 + lane];
        ushort2 v1 = h2[(size_t)d1 * 64 + lane];
        ushort2 v2 = h2[(size_t)d2i * 64 + lane];
        ushort2 v3 = h2[(size_t)d3 * 64 + lane];
        acc.x += a0 * bf2f(v0.x) + a1 * bf2f(v1.x) + a2 * bf2f(v2.x) + a3 * bf2f(v3.x);
        acc.y += a0 * bf2f(v0.y) + a1 * bf2f(v1.y) + a2 * bf2f(v2.y) + a3 * bf2f(v3.y);
    }
    for (; j < n2; ++j) {
        int d0 = s_dst[wid][j]; float a0 = s_al[wid][j];
        ushort2 v0 = h2[(size_t)d0 * 64 + lane];
        acc.x += a0 * bf2f(v0.x); acc.y += a0 * bf2f(v0.y);
    }
    for (; j < deg; ++j) {                            // slow path: deg > CAP
        int dst = adj[beg + j];
        float e = sl + s_r[dst];
        e = (e >= 0.f) ? e : 0.2f * e;
        float a0 = __expf(e - m) * inv;
        ushort2 v0 = h2[(size_t)dst * 64 + lane];
        acc.x += a0 * bf2f(v0.x); acc.y += a0 * bf2f(v0.y);
    }
    ((float2*)out)[(size_t)node * 64 + lane] = acc;
}

extern "C" void kernel_launch(void* const* d_in, const int* in_sizes, int n_in,
                              void* d_out, int out_size, void* d_ws, size_t ws_size,
                              hipStream_t stream) {
    const float* x  = (const float*)d_in[0];
    const int*   ei = (const int*)d_in[1];      // [0,E) = src, [E,2E) = dst
    const float* w  = (const float*)d_in[2];
    const float* a  = (const float*)d_in[3];
    float* out = (float*)d_out;

    // workspace layout (4-byte words)
    unsigned short* hq = (unsigned short*)d_ws;             // GN*128 bf16
    float* s_l     = (float*)(hq + (size_t)GN * 128);       // GN
    float* s_r     = s_l + GN;                              // GN
    int*   bcnt    = (int*)(s_r + GN);                      // NB   (zeroed with s_l/s_r)
    int*   bbase   = bcnt + NB;                             // NB+1
    int*   bcursor = bbase + NB + 1;                        // NB
    int*   rowptr  = bcursor + NB;                          // GN+1
    unsigned* binned = (unsigned*)(rowptr + GN + 1);        // GE
    int*   adj     = (int*)(binned + GE);                   // GE
    unsigned short* wT = (unsigned short*)(adj + GE);       // 128*256 bf16

    hipMemsetAsync(s_l, 0, (size_t)(2 * GN + NB) * sizeof(float), stream);  // s_l, s_r, bcnt

    wprep_kernel<<<32, 256, 0, stream>>>(w, wT);
    gemm_kernel<<<(GN + 127) / 128, 256, 0, stream>>>(x, wT, a, hq, s_l, s_r);
    bhist_kernel<<<(GE + CHUNK - 1) / CHUNK, 256, 0, stream>>>(ei, bcnt);
    bscan_kernel<<<1, 64, 0, stream>>>(bcnt, bbase, bcursor);
    bin_kernel<<<(GE + CHUNK - 1) / CHUNK, 256, 0, stream>>>(ei, bcursor, binned);
    fine_kernel<<<NB, 256, 0, stream>>>(binned, bbase, rowptr, adj);
    aggregate_kernel<<<GN / 4, 256, 0, stream>>>((const ushort2*)hq, s_l, s_r, rowptr, adj, out);
}